// Round 5
// baseline (1394.388 us; speedup 1.0000x reference)
//
#include <hip/hip_runtime.h>

// 2-layer stacked LSTM (shared cell), B=256, T=1024, F=UNITS=128 — MFMA v2.
// 64 LSTM WGs (512 thr, 8 waves) x 4 batch rows; blocks 64..255 fill zeros.
//
// Single fused MFMA chain per tick, K=256 concat, B = [W;U]:
//   A rows 0-3: [x_b(k)   | h1_b(k-1)]  -> z1 rows (cell1 step k)
//   A rows 4-7: [h1_b(k-1)| h2_b(k-2)]  -> z2 rows (cell2 step k-1)
//   A rows 8-15: zero (never written)   -> harmless M padding
// Per wave: 16 units x 4 gates = 64 cols, 8 k-tiles -> 32 MFMA/tick.
// z exchange via zlds[8][129] float4 (skewed stride): each lane then does
// exactly 2 gate-evals (batch lc, cell1 + cell2) -> trans work halved and
// spread across all lanes. 2 barriers/tick.
//
// d_out (f32): [0,32768) h2_final | [32768,+33554432) zeros | [33587200,..) c1

typedef _Float16 f16;
typedef _Float16 f16x2 __attribute__((ext_vector_type(2)));
typedef _Float16 f16x8 __attribute__((ext_vector_type(8)));
typedef float    f32x4 __attribute__((ext_vector_type(4)));

#define T_STEPS 1024
#define UNITS   128
#define NLSTM   64      // LSTM workgroups
#define BPW     4       // batch rows per LSTM WG
#define NBLK    256
#define OUT_ZERO 32768
#define OUT_C1   33587200
#define ROWB    512     // bytes per A row (256 f16)
#define ABUF_B  (16*ROWB)   // 8 KiB per buffer

__device__ __forceinline__ float frcp_(float x) {
#if __has_builtin(__builtin_amdgcn_rcpf)
    return __builtin_amdgcn_rcpf(x);
#else
    return 1.0f / x;
#endif
}
__device__ __forceinline__ float sigmoidf_(float x) {
    return frcp_(1.0f + __expf(-x));
}
__device__ __forceinline__ float tanhf_(float x) {
    float e = __expf(2.0f * x);
    return 1.0f - 2.0f * frcp_(e + 1.0f);
}
__device__ __forceinline__ unsigned pkh(float a, float b) {
    f16x2 t; t[0] = (f16)a; t[1] = (f16)b;
    return __builtin_bit_cast(unsigned, t);
}
__device__ __forceinline__ unsigned short hbits(float a) {
    f16 t = (f16)a;
    return __builtin_bit_cast(unsigned short, t);
}
// swizzled byte address within a 16-row x 512B A buffer (XOR 16B slot by row)
__device__ __forceinline__ int swb(int row, int byteoff) {
    return row * ROWB + ((((byteoff >> 4) ^ (row & 7)) << 4) | (byteoff & 15));
}

__global__ __launch_bounds__(512, 2) void lstm2_kernel(
    const float* __restrict__ X,   // [256][1024][128]
    const float* __restrict__ W,   // [128][512] gate order i|f|g|o
    const float* __restrict__ U,   // [128][512]
    const float* __restrict__ Bv,  // [512]
    float* __restrict__ out)
{
    const int blk = blockIdx.x;
    const int tid = threadIdx.x;

    if (blk >= NLSTM) {
        // ---------- zeros-output fill on idle CUs ----------
        const size_t nthr = (size_t)(NBLK - NLSTM) * 512;
        float4* dst = (float4*)(out + OUT_ZERO);
        const float4 z4 = make_float4(0.f, 0.f, 0.f, 0.f);
        for (size_t i = (size_t)(blk - NLSTM) * 512 + tid; i < 8388608u; i += nthr)
            dst[i] = z4;
        return;
    }

    // ---------- LSTM workgroup ----------
    const int w  = tid >> 6;        // wave: unit block [16w, 16w+16)
    const int l  = tid & 63;
    const int lr = l & 15;          // A row / B col-in-tile
    const int lc = l >> 4;          // k-sub / C row group / owned batch row
    const int u  = w * 16 + lr;     // unit in [0,128)
    const int b0 = blk * BPW;

    __shared__ __align__(16) char   Ab[2][ABUF_B];
    __shared__ __align__(16) float4 zlds[8][129];   // [row][unit], skewed

    // ---- B-fragments (resident): Bf[gate][kt], k_global = kt*32+lc*8+j
    f16x8 Bf[4][8];
    #pragma unroll
    for (int g = 0; g < 4; ++g) {
        #pragma unroll
        for (int kt = 0; kt < 8; ++kt) {
            f16x8 t;
            #pragma unroll
            for (int j = 0; j < 8; ++j) {
                const int kg = kt * 32 + lc * 8 + j;
                const float v = (kg < 128) ? W[(size_t)kg * 512 + g * 128 + u]
                                           : U[(size_t)(kg - 128) * 512 + g * 128 + u];
                t[j] = (f16)v;
            }
            Bf[g][kt] = t;
        }
    }
    float bias[4];
    #pragma unroll
    for (int g = 0; g < 4; ++g) bias[g] = Bv[g * 128 + u];

    // ---- init LDS: zero both A buffers, then x[0] into buf0 rows 0-3 (k-low)
    for (int i = tid; i < 2 * ABUF_B / 16; i += 512) ((float4*)Ab)[i] = make_float4(0.f,0.f,0.f,0.f);
    __syncthreads();
    if (tid < 256) {
        const int flat = tid * 2, xr = flat >> 7, xc = flat & 127;
        const float2 xv = *(const float2*)(X + (size_t)(b0 + xr) * (T_STEPS * UNITS) + xc);
        *(unsigned*)(&Ab[0][0] + swb(xr, xc * 2)) = pkh(xv.x, xv.y);
    }
    __syncthreads();

    // precomputed A-frag addresses (row lr, 16B slice per kt)
    int ard[8];
    #pragma unroll
    for (int kt = 0; kt < 8; ++kt) ard[kt] = swb(lr, kt * 64 + lc * 16);

    float c1 = 0.f, c2 = 0.f;

    for (int k = 0; k <= T_STEPS; ++k) {
        const int rdo = (k & 1) * ABUF_B, wro = ABUF_B - rdo;
        char* Abr = &Ab[0][0] + rdo;
        char* Abw = &Ab[0][0] + wro;

        // x[k+1] prefetch (issue early; consumed after barrier 2 region)
        float xa = 0.f, xb = 0.f; int xr = 0, xc = 0;
        if (tid < 256 && k + 1 < T_STEPS) {
            const int flat = tid * 2; xr = flat >> 7; xc = flat & 127;
            const float2 xv = *(const float2*)(X + (size_t)(b0 + xr) * (T_STEPS * UNITS)
                                                 + (size_t)(k + 1) * UNITS + xc);
            xa = xv.x; xb = xv.y;
        }

        // ---- A fragments + MFMA chain (rows 8-15 are zeros)
        f16x8 Af[8];
        #pragma unroll
        for (int kt = 0; kt < 8; ++kt) Af[kt] = *(const f16x8*)(Abr + ard[kt]);

        f32x4 acc[4];
        #pragma unroll
        for (int g = 0; g < 4; ++g) acc[g] = f32x4{0.f, 0.f, 0.f, 0.f};
        #pragma unroll
        for (int kt = 0; kt < 8; ++kt)
            #pragma unroll
            for (int g = 0; g < 4; ++g)
                acc[g] = __builtin_amdgcn_mfma_f32_16x16x32_f16(Af[kt], Bf[g][kt], acc[g], 0, 0, 0);

        // ---- publish z rows 0-7 (C row = 4*lc+e valid for lc<2)
        if (lc < 2) {
            #pragma unroll
            for (int e = 0; e < 4; ++e)
                zlds[4 * lc + e][u] = make_float4(acc[0][e], acc[1][e], acc[2][e], acc[3][e]);
        }
        __syncthreads();

        // ---- epilogue: each lane does (batch lc, cell1) and (batch lc, cell2)
        const float4 z1 = *(const float4*)&zlds[lc][u];
        const float4 z2 = *(const float4*)&zlds[4 + lc][u];

        if (k < T_STEPS) {
            const float i1 = sigmoidf_(z1.x + bias[0]);
            const float f1 = sigmoidf_(z1.y + bias[1]);
            const float g1 = tanhf_(z1.z + bias[2]);
            const float o1 = sigmoidf_(z1.w + bias[3]);
            c1 = f1 * c1 + i1 * g1;
            const float h1v = o1 * tanhf_(c1);
            const unsigned short hb = hbits(h1v);
            *(unsigned short*)(Abw + swb(lc,     256 + u * 2)) = hb;  // z1's U-part
            *(unsigned short*)(Abw + swb(4 + lc, u * 2))       = hb;  // z2's W-part
            if (k == T_STEPS - 1)
                out[OUT_C1 + (size_t)(b0 + lc) * UNITS + u] = c1;
        }
        if (k > 0) {
            const float i2 = sigmoidf_(z2.x + bias[0]);
            const float f2 = sigmoidf_(z2.y + bias[1]);
            const float g2 = tanhf_(z2.z + bias[2]);
            const float o2 = sigmoidf_(z2.w + bias[3]);
            c2 = f2 * c2 + i2 * g2;
            const float h2v = o2 * tanhf_(c2);
            if (k < T_STEPS)
                *(unsigned short*)(Abw + swb(4 + lc, 256 + u * 2)) = hbits(h2v);
            else
                out[(size_t)(b0 + lc) * UNITS + u] = h2v;   // h2 final
        }
        if (tid < 256 && k + 1 < T_STEPS)
            *(unsigned*)(Abw + swb(xr, xc * 2)) = pkh(xa, xb);

        __syncthreads();
    }
}

extern "C" void kernel_launch(void* const* d_in, const int* in_sizes, int n_in,
                              void* d_out, int out_size, void* d_ws, size_t ws_size,
                              hipStream_t stream) {
    const float* X  = (const float*)d_in[0];
    const float* W  = (const float*)d_in[1];
    const float* U  = (const float*)d_in[2];
    const float* Bv = (const float*)d_in[3];
    float* out = (float*)d_out;
    hipLaunchKernelGGL(lstm2_kernel, dim3(NBLK), dim3(512), 0, stream,
                       X, W, U, Bv, out);
}

// Round 6
// 1346.139 us; speedup vs baseline: 1.0358x; 1.0358x over previous
//
#include <hip/hip_runtime.h>

// 2-layer stacked LSTM (shared cell), B=256, T=1024, F=UNITS=128 — MFMA v3.
// 32 LSTM WGs (512 thr, 8 waves) x 8 batch rows (full M=16 = 8 batch x 2
// cells); blocks 32..255 fill the zeros output.
//
// Per tick k: z1 = x[k]@W + h1[k-1]@U (cell1 step k),
//             z2 = h1[k-1]@W + h2[k-2]@U (cell2 step k-1).
// A1 = buffer rows 0-15 [x; h1], A2 = rows 8-23 [h1; h2]; z = A1@W + A2@U.
// acc rows 0-7 = z1 batch 0-7, rows 8-15 = z2 batch 0-7. Epilogue is
// acc-lane-local (C: col=lane&15, row=4*(lane>>4)+e); lanes lc<2 run cell1,
// lc>=2 run cell2 — same instruction stream. One barrier per tick.
// Gate chains emitted in pairs (i,f) then (g,o) with activations of the
// first pair between: trans ops hide under the second pair's MFMA time.
// h writes packed to b32 via shfl_xor(1) (conflict-free).
//
// d_out (f32): [0,32768) h2_final | [32768,+33554432) zeros | [33587200,..) c1

typedef _Float16 f16;
typedef _Float16 f16x2 __attribute__((ext_vector_type(2)));
typedef _Float16 f16x8 __attribute__((ext_vector_type(8)));
typedef float    f32x4 __attribute__((ext_vector_type(4)));

#define T_STEPS 1024
#define UNITS   128
#define NLSTM   32
#define BPW     8
#define NBLK    256
#define OUT_ZERO 32768
#define OUT_C1   33587200
#define ROWB    256            // bytes per buffer row (128 f16)
#define BUFB    (24 * ROWB)    // 6 KiB per buffer (x:0-7, h1:8-15, h2:16-23)

__device__ __forceinline__ float frcp_(float x) {
#if __has_builtin(__builtin_amdgcn_rcpf)
    return __builtin_amdgcn_rcpf(x);
#else
    return 1.0f / x;
#endif
}
__device__ __forceinline__ float sigmoidf_(float x) {
    return frcp_(1.0f + __expf(-x));
}
__device__ __forceinline__ float tanhf_(float x) {
    float e = __expf(2.0f * x);
    return 1.0f - 2.0f * frcp_(e + 1.0f);
}
__device__ __forceinline__ unsigned pkh(float a, float b) {
    f16x2 t; t[0] = (f16)a; t[1] = (f16)b;
    return __builtin_bit_cast(unsigned, t);
}
// swizzled byte address in the A buffer (XOR 16B slot by row&7)
__device__ __forceinline__ int swb(int row, int byteoff) {
    return row * ROWB + (byteoff ^ ((row & 7) << 4));
}

__global__ __launch_bounds__(512, 2) void lstm2_kernel(
    const float* __restrict__ X,   // [256][1024][128]
    const float* __restrict__ W,   // [128][512] gate order i|f|g|o
    const float* __restrict__ U,   // [128][512]
    const float* __restrict__ Bv,  // [512]
    float* __restrict__ out)
{
    const int blk = blockIdx.x;
    const int tid = threadIdx.x;

    if (blk >= NLSTM) {
        // ---------- zeros-output fill on idle CUs ----------
        const size_t nthr = (size_t)(NBLK - NLSTM) * 512;
        float4* dst = (float4*)(out + OUT_ZERO);
        const float4 z4 = make_float4(0.f, 0.f, 0.f, 0.f);
        for (size_t i = (size_t)(blk - NLSTM) * 512 + tid; i < 8388608u; i += nthr)
            dst[i] = z4;
        return;
    }

    // ---------- LSTM workgroup ----------
    const int w  = tid >> 6;        // wave: unit block [16w, 16w+16)
    const int l  = tid & 63;
    const int lr = l & 15;          // A row / C col (unit within block)
    const int lc = l >> 4;          // k-sub / C row group
    const int u  = w * 16 + lr;     // unit in [0,128)
    const int b0 = blk * BPW;
    const bool cell2 = (lc >= 2);

    __shared__ __align__(16) char Abuf[2][BUFB];
    char* Ab = &Abuf[0][0];

    // ---- weight B-fragments (resident): [gate][kt], K=128 per matrix
    f16x8 Wf[4][4], Uf[4][4];
    #pragma unroll
    for (int g = 0; g < 4; ++g) {
        #pragma unroll
        for (int kt = 0; kt < 4; ++kt) {
            f16x8 wt, ut;
            #pragma unroll
            for (int j = 0; j < 8; ++j) {
                const int kg = kt * 32 + lc * 8 + j;
                wt[j] = (f16)W[(size_t)kg * 512 + g * 128 + u];
                ut[j] = (f16)U[(size_t)kg * 512 + g * 128 + u];
            }
            Wf[g][kt] = wt;  Uf[g][kt] = ut;
        }
    }
    float bias[4];
    #pragma unroll
    for (int g = 0; g < 4; ++g) bias[g] = Bv[g * 128 + u];

    // ---- init LDS: zero both buffers; x[0] -> buf0 rows 0-7
    for (int i = tid; i < 2 * BUFB / 4; i += 512) ((float*)Ab)[i] = 0.0f;
    __syncthreads();
    {
        const int flat = tid * 2, xr = flat >> 7, xc = flat & 127;
        const float2 xv = *(const float2*)(X + (size_t)(b0 + xr) * (T_STEPS * UNITS) + xc);
        *(unsigned*)(Ab + swb(xr, xc * 2)) = pkh(xv.x, xv.y);
    }
    __syncthreads();

    // precomputed A-frag addresses: A1 row lr, A2 row 8+lr
    int ard1[4], ard2[4];
    #pragma unroll
    for (int kt = 0; kt < 4; ++kt) {
        ard1[kt] = swb(lr,     kt * 64 + lc * 16);
        ard2[kt] = swb(8 + lr, kt * 64 + lc * 16);
    }

    float cst[4] = {0.f, 0.f, 0.f, 0.f};   // c1 (lc<2) / c2 (lc>=2)

    for (int k = 0; k <= T_STEPS; ++k) {
        const int rdo = (k & 1) * BUFB, wro = BUFB - rdo;
        char* Abr = Ab + rdo;
        char* Abw = Ab + wro;

        // x[k+1] prefetch (global, in flight under MFMA phase)
        float xa = 0.f, xb = 0.f;
        const int xr = tid >> 6, xc = (tid * 2) & 127;
        if (k + 1 < T_STEPS) {
            const float2 xv = *(const float2*)(X + (size_t)(b0 + xr) * (T_STEPS * UNITS)
                                                 + (size_t)(k + 1) * UNITS + xc);
            xa = xv.x; xb = xv.y;
        }

        // ---- A fragments
        f16x8 A1[4], A2[4];
        #pragma unroll
        for (int kt = 0; kt < 4; ++kt) {
            A1[kt] = *(const f16x8*)(Abr + ard1[kt]);
            A2[kt] = *(const f16x8*)(Abr + ard2[kt]);
        }

        // ---- gate pair (i,f): chains then activations
        f32x4 ai = {0.f,0.f,0.f,0.f}, af = {0.f,0.f,0.f,0.f};
        #pragma unroll
        for (int kt = 0; kt < 4; ++kt) {
            ai = __builtin_amdgcn_mfma_f32_16x16x32_f16(A1[kt], Wf[0][kt], ai, 0, 0, 0);
            af = __builtin_amdgcn_mfma_f32_16x16x32_f16(A1[kt], Wf[1][kt], af, 0, 0, 0);
        }
        #pragma unroll
        for (int kt = 0; kt < 4; ++kt) {
            ai = __builtin_amdgcn_mfma_f32_16x16x32_f16(A2[kt], Uf[0][kt], ai, 0, 0, 0);
            af = __builtin_amdgcn_mfma_f32_16x16x32_f16(A2[kt], Uf[1][kt], af, 0, 0, 0);
        }
        float si[4], sf[4];
        #pragma unroll
        for (int e = 0; e < 4; ++e) {
            si[e] = sigmoidf_(ai[e] + bias[0]);     // hides under (g,o) MFMAs
            sf[e] = sigmoidf_(af[e] + bias[1]);
        }

        // ---- gate pair (g,o): chains then activations
        f32x4 ag = {0.f,0.f,0.f,0.f}, ao = {0.f,0.f,0.f,0.f};
        #pragma unroll
        for (int kt = 0; kt < 4; ++kt) {
            ag = __builtin_amdgcn_mfma_f32_16x16x32_f16(A1[kt], Wf[2][kt], ag, 0, 0, 0);
            ao = __builtin_amdgcn_mfma_f32_16x16x32_f16(A1[kt], Wf[3][kt], ao, 0, 0, 0);
        }
        #pragma unroll
        for (int kt = 0; kt < 4; ++kt) {
            ag = __builtin_amdgcn_mfma_f32_16x16x32_f16(A2[kt], Uf[2][kt], ag, 0, 0, 0);
            ao = __builtin_amdgcn_mfma_f32_16x16x32_f16(A2[kt], Uf[3][kt], ao, 0, 0, 0);
        }

        // ---- combine + state update (per-lane cell select, no divergence)
        const bool active = cell2 ? (k > 0) : (k < T_STEPS);
        float hq[4];
        #pragma unroll
        for (int e = 0; e < 4; ++e) {
            const float gg = tanhf_(ag[e] + bias[2]);
            const float og = sigmoidf_(ao[e] + bias[3]);
            const float cn = sf[e] * cst[e] + si[e] * gg;
            if (active) cst[e] = cn;
            hq[e] = og * tanhf_(cn);
        }

        // ---- packed h writes: pair units (u, u+1) -> one b32 per even lane
        const bool wact = active && (k < T_STEPS);
        #pragma unroll
        for (int e = 0; e < 4; ++e) {
            const float hp = __shfl_xor(hq[e], 1);
            if (wact && !(lr & 1))
                *(unsigned*)(Abw + swb(8 + 4 * lc + e, u * 2)) = pkh(hq[e], hp);
        }

        // ---- final outputs
        if (k == T_STEPS - 1 && !cell2) {
            #pragma unroll
            for (int e = 0; e < 4; ++e)
                out[OUT_C1 + (size_t)(b0 + 4 * lc + e) * UNITS + u] = cst[e];
        }
        if (k == T_STEPS && cell2) {
            #pragma unroll
            for (int e = 0; e < 4; ++e)
                out[(size_t)(b0 + 4 * lc + e - 8) * UNITS + u] = hq[e];
        }

        // ---- x[k+1] -> write buffer rows 0-7
        if (k + 1 < T_STEPS)
            *(unsigned*)(Abw + swb(xr, xc * 2)) = pkh(xa, xb);

        __syncthreads();
    }
}

extern "C" void kernel_launch(void* const* d_in, const int* in_sizes, int n_in,
                              void* d_out, int out_size, void* d_ws, size_t ws_size,
                              hipStream_t stream) {
    const float* X  = (const float*)d_in[0];
    const float* W  = (const float*)d_in[1];
    const float* U  = (const float*)d_in[2];
    const float* Bv = (const float*)d_in[3];
    float* out = (float*)d_out;
    hipLaunchKernelGGL(lstm2_kernel, dim3(NBLK), dim3(512), 0, stream,
                       X, W, U, Bv, out);
}

// Round 7
// 1207.194 us; speedup vs baseline: 1.1551x; 1.1151x over previous
//
#include <hip/hip_runtime.h>

// 2-layer stacked LSTM (shared cell), B=256, T=1024, F=UNITS=128 — MFMA v4.
// = round-3 structure (1186us) + setprio wave-stagger + bias-in-acc-init.
//
// 32 LSTM WGs (512 thr, 8 waves) x 8 batch rows (full M=16 = 8 batch x 2
// cells); blocks 32..255 fill the zeros output.
//
// Per tick k: acc = A1@W + A2@U, A1 = rows 0-15 [x(k); h1(k-1)],
// A2 = rows 8-23 [h1(k-1); h2(k-2)].  acc rows 0-7 = z1 (cell1 step k),
// rows 8-15 = z2 (cell2 step k-1). Epilogue acc-lane-local; lanes lc<2 run
// cell1, lc>=2 run cell2 (same instruction stream). One barrier per tick.
//
// Wave-stagger: waves 0-3 (one per SIMD) get s_setprio(1) during the MFMA
// block -> they drain the matrix pipe first and run their trans-pipe
// epilogue while the SIMD-mate wave (prio 0) issues its MFMAs. Only the
// mate's epilogue tail stays exposed.
//
// d_out (f32): [0,32768) h2_final | [32768,+33554432) zeros | [33587200,..) c1

typedef _Float16 f16;
typedef _Float16 f16x2 __attribute__((ext_vector_type(2)));
typedef _Float16 f16x8 __attribute__((ext_vector_type(8)));
typedef float    f32x4 __attribute__((ext_vector_type(4)));

#define T_STEPS 1024
#define UNITS   128
#define NLSTM   32
#define BPW     8
#define NBLK    256
#define OUT_ZERO 32768
#define OUT_C1   33587200
#define BUFB    6144   // 24 rows * 256B (x:0-7, h1:8-15, h2:16-23)

__device__ __forceinline__ float frcp_(float x) {
#if __has_builtin(__builtin_amdgcn_rcpf)
    return __builtin_amdgcn_rcpf(x);
#else
    return 1.0f / x;
#endif
}
__device__ __forceinline__ float sigmoidf_(float x) {
    return frcp_(1.0f + __expf(-x));
}
__device__ __forceinline__ float tanhf_(float x) {
    float e = __expf(2.0f * x);
    return 1.0f - 2.0f * frcp_(e + 1.0f);
}
__device__ __forceinline__ unsigned pkh(float a, float b) {
    f16x2 t; t[0] = (f16)a; t[1] = (f16)b;
    return __builtin_bit_cast(unsigned, t);
}

__global__ __launch_bounds__(512, 2) void lstm2_kernel(
    const float* __restrict__ X,   // [256][1024][128]
    const float* __restrict__ W,   // [128][512] gate order i|f|g|o
    const float* __restrict__ U,   // [128][512]
    const float* __restrict__ Bv,  // [512]
    float* __restrict__ out)
{
    const int blk = blockIdx.x;
    const int tid = threadIdx.x;

    if (blk >= NLSTM) {
        // ---------- zeros-output fill on idle CUs ----------
        const size_t nthr = (size_t)(NBLK - NLSTM) * 512;
        float4* dst = (float4*)(out + OUT_ZERO);
        const float4 z4 = make_float4(0.f, 0.f, 0.f, 0.f);
        for (size_t i = (size_t)(blk - NLSTM) * 512 + tid; i < 8388608u; i += nthr)
            dst[i] = z4;
        return;
    }

    // ---------- LSTM workgroup ----------
    const int w  = tid >> 6;        // wave = unit block [16w,16w+16)
    const int l  = tid & 63;
    const int lr = l & 15;          // A row / C col (unit within block)
    const int lc = l >> 4;          // k-chunk / C row group
    const int u  = w * 16 + lr;     // unit in [0,128)
    const int b0 = blk * BPW;
    const bool cell2 = (l >= 32);
    const bool prio_wave = (w < 4); // one per SIMD

    __shared__ __align__(16) char Abuf[2][BUFB];
    char* Ab = (char*)Abuf;

    // ---- weight B-fragments (resident): [gate][ktile], 8 f16 each
    f16x8 Wf[4][4], Uf[4][4];
    #pragma unroll
    for (int g = 0; g < 4; ++g) {
        #pragma unroll
        for (int kt = 0; kt < 4; ++kt) {
            f16x8 wt, ut;
            #pragma unroll
            for (int j = 0; j < 8; ++j) {
                const int krow = kt * 32 + lc * 8 + j;
                wt[j] = (f16)W[(size_t)krow * 512 + g * 128 + u];
                ut[j] = (f16)U[(size_t)krow * 512 + g * 128 + u];
            }
            Wf[g][kt] = wt;  Uf[g][kt] = ut;
        }
    }
    float bias[4];
    #pragma unroll
    for (int g = 0; g < 4; ++g) bias[g] = Bv[g * 128 + u];

    // ---- precomputed swizzled addresses (lane constants)
    const int swz = (lr & 7) << 4;
    int raddr[2][4];
    #pragma unroll
    for (int a0 = 0; a0 < 2; ++a0)
        #pragma unroll
        for (int kt = 0; kt < 4; ++kt)
            raddr[a0][kt] = (((a0 * 8 + lr) * 256) + kt * 64 + lc * 16) ^ swz;
    int waddr[4];
    #pragma unroll
    for (int e = 0; e < 4; ++e)
        waddr[e] = ((8 + 4 * lc + e) * 256 + u * 2) ^ ((((4 * lc + e) & 7)) << 4);

    // ---- init LDS: zero both buffers, load x[0] into buf0 rows 0-7
    for (int i = tid; i < 3072; i += 512) ((float*)Ab)[i] = 0.0f;
    {
        const int flat = tid * 2, xr = flat >> 7, xc = flat & 127;
        const float2 xv = *(const float2*)(X + (size_t)(b0 + xr) * (T_STEPS * UNITS) + xc);
        const int byte = ((xr * 256 + xc * 2) ^ ((xr & 7) << 4));
        *(unsigned*)(Ab + byte) = pkh(xv.x, xv.y);
    }
    __syncthreads();

    float cst[4] = {0.f, 0.f, 0.f, 0.f};   // c1 (lanes<32) / c2 (lanes>=32)

    for (int k = 0; k <= T_STEPS; ++k) {
        const int rdo = (k & 1) * BUFB, wro = BUFB - rdo;

        // issue x[k+1] prefetch early (hides HBM latency under MFMA phase)
        float xa = 0.f, xb = 0.f; int xr = 0, xc = 0;
        if (k + 1 < T_STEPS) {
            const int flat = tid * 2; xr = flat >> 7; xc = flat & 127;
            const float2 xv = *(const float2*)(X + (size_t)(b0 + xr) * (T_STEPS * UNITS)
                                                 + (size_t)(k + 1) * UNITS + xc);
            xa = xv.x; xb = xv.y;
        }

        // ---- A fragments from LDS (conflict-free via swizzle)
        f16x8 A1[4], A2[4];
        #pragma unroll
        for (int kt = 0; kt < 4; ++kt) {
            A1[kt] = *(const f16x8*)(Ab + rdo + raddr[0][kt]);
            A2[kt] = *(const f16x8*)(Ab + rdo + raddr[1][kt]);
        }

        // ---- MFMA block: acc rows 0-7 = z1, rows 8-15 = z2
        if (prio_wave) __builtin_amdgcn_s_setprio(1);
        f32x4 acc[4];
        #pragma unroll
        for (int g = 0; g < 4; ++g)
            acc[g] = f32x4{bias[g], bias[g], bias[g], bias[g]};
        #pragma unroll
        for (int kt = 0; kt < 4; ++kt)
            #pragma unroll
            for (int g = 0; g < 4; ++g)
                acc[g] = __builtin_amdgcn_mfma_f32_16x16x32_f16(A1[kt], Wf[g][kt], acc[g], 0, 0, 0);
        #pragma unroll
        for (int kt = 0; kt < 4; ++kt)
            #pragma unroll
            for (int g = 0; g < 4; ++g)
                acc[g] = __builtin_amdgcn_mfma_f32_16x16x32_f16(A2[kt], Uf[g][kt], acc[g], 0, 0, 0);
        if (prio_wave) __builtin_amdgcn_s_setprio(0);

        // ---- epilogue: lanes<32 cell1 (k<T), lanes>=32 cell2 (k>0)
        const bool active = cell2 ? (k > 0) : (k < T_STEPS);
        float hq[4];
        #pragma unroll
        for (int e = 0; e < 4; ++e) {
            const float ig = sigmoidf_(acc[0][e]);
            const float fg = sigmoidf_(acc[1][e]);
            const float gg = tanhf_(acc[2][e]);
            const float og = sigmoidf_(acc[3][e]);
            const float cn = fg * cst[e] + ig * gg;
            if (active) cst[e] = cn;
            hq[e] = og * tanhf_(cn);
        }

        // ---- write h1/h2 to wr buffer (row = 8 + 4*lc + e for both halves)
        if (active && k < T_STEPS) {
            #pragma unroll
            for (int e = 0; e < 4; ++e)
                *(f16*)(Ab + wro + waddr[e]) = (f16)hq[e];
        }
        // ---- write x[k+1] to wr buffer rows 0-7
        if (k + 1 < T_STEPS) {
            const int byte = ((xr * 256 + xc * 2) ^ ((xr & 7) << 4));
            *(unsigned*)(Ab + wro + byte) = pkh(xa, xb);
        }

        // ---- final outputs
        if (k == T_STEPS - 1 && !cell2) {
            #pragma unroll
            for (int e = 0; e < 4; ++e)
                out[OUT_C1 + (size_t)(b0 + 4 * lc + e) * UNITS + u] = cst[e];
        }
        if (k == T_STEPS && cell2) {
            #pragma unroll
            for (int e = 0; e < 4; ++e)
                out[(size_t)(b0 + 4 * lc + e - 8) * UNITS + u] = hq[e];
        }
        __syncthreads();
    }
}

extern "C" void kernel_launch(void* const* d_in, const int* in_sizes, int n_in,
                              void* d_out, int out_size, void* d_ws, size_t ws_size,
                              hipStream_t stream) {
    const float* X  = (const float*)d_in[0];
    const float* W  = (const float*)d_in[1];
    const float* U  = (const float*)d_in[2];
    const float* Bv = (const float*)d_in[3];
    float* out = (float*)d_out;
    hipLaunchKernelGGL(lstm2_kernel, dim3(NBLK), dim3(512), 0, stream,
                       X, W, U, Bv, out);
}

// Round 8
// 1102.284 us; speedup vs baseline: 1.2650x; 1.0952x over previous
//
#include <hip/hip_runtime.h>

// 2-layer stacked LSTM (shared cell), B=256, T=1024, F=UNITS=128 — MFMA v5.
// = round-3 structure (1186us) + split gate chains (g,o first; i,f second)
//   with the g/o transcendentals hand-spliced between the i/f MFMAs so the
//   trans pipe retires work while the matrix pipe stays fed (in-order wave
//   stream => both pipes busy). Tail = sigma(i,f) + c/h update only.
//
// 32 LSTM WGs (512 thr, 8 waves) x 8 batch rows (full M=16 = 8 batch x 2
// cells); blocks 32..255 fill the zeros output.
//
// Per tick k: acc = A1@W + A2@U, A1 = rows 0-15 [x(k); h1(k-1)],
// A2 = rows 8-23 [h1(k-1); h2(k-2)].  acc rows 0-7 = z1 (cell1 step k),
// rows 8-15 = z2 (cell2 step k-1). Epilogue acc-lane-local; lanes lc<2 run
// cell1, lc>=2 run cell2 (same instruction stream). One barrier per tick.
//
// d_out (f32): [0,32768) h2_final | [32768,+33554432) zeros | [33587200,..) c1

typedef _Float16 f16;
typedef _Float16 f16x2 __attribute__((ext_vector_type(2)));
typedef _Float16 f16x8 __attribute__((ext_vector_type(8)));
typedef float    f32x4 __attribute__((ext_vector_type(4)));

#define T_STEPS 1024
#define UNITS   128
#define NLSTM   32
#define BPW     8
#define NBLK    256
#define OUT_ZERO 32768
#define OUT_C1   33587200
#define BUFB    6144   // 24 rows * 256B (x:0-7, h1:8-15, h2:16-23)

#define MFMA16(A, B, C) __builtin_amdgcn_mfma_f32_16x16x32_f16((A), (B), (C), 0, 0, 0)

__device__ __forceinline__ float frcp_(float x) {
#if __has_builtin(__builtin_amdgcn_rcpf)
    return __builtin_amdgcn_rcpf(x);
#else
    return 1.0f / x;
#endif
}
__device__ __forceinline__ float sigmoidf_(float x) {
    return frcp_(1.0f + __expf(-x));
}
__device__ __forceinline__ float tanhf_(float x) {
    float e = __expf(2.0f * x);
    return 1.0f - 2.0f * frcp_(e + 1.0f);
}
__device__ __forceinline__ unsigned pkh(float a, float b) {
    f16x2 t; t[0] = (f16)a; t[1] = (f16)b;
    return __builtin_bit_cast(unsigned, t);
}

__global__ __launch_bounds__(512, 2) void lstm2_kernel(
    const float* __restrict__ X,   // [256][1024][128]
    const float* __restrict__ W,   // [128][512] gate order i|f|g|o
    const float* __restrict__ U,   // [128][512]
    const float* __restrict__ Bv,  // [512]
    float* __restrict__ out)
{
    const int blk = blockIdx.x;
    const int tid = threadIdx.x;

    if (blk >= NLSTM) {
        // ---------- zeros-output fill on idle CUs ----------
        const size_t nthr = (size_t)(NBLK - NLSTM) * 512;
        float4* dst = (float4*)(out + OUT_ZERO);
        const float4 z4 = make_float4(0.f, 0.f, 0.f, 0.f);
        for (size_t i = (size_t)(blk - NLSTM) * 512 + tid; i < 8388608u; i += nthr)
            dst[i] = z4;
        return;
    }

    // ---------- LSTM workgroup ----------
    const int w  = tid >> 6;        // wave = unit block [16w,16w+16)
    const int l  = tid & 63;
    const int lr = l & 15;          // A row / C col (unit within block)
    const int lc = l >> 4;          // k-chunk / C row group
    const int u  = w * 16 + lr;     // unit in [0,128)
    const int b0 = blk * BPW;
    const bool cell2 = (l >= 32);

    __shared__ __align__(16) char Abuf[2][BUFB];
    char* Ab = (char*)Abuf;

    // ---- weight B-fragments (resident): [gate][ktile], 8 f16 each
    f16x8 Wf[4][4], Uf[4][4];
    #pragma unroll
    for (int g = 0; g < 4; ++g) {
        #pragma unroll
        for (int kt = 0; kt < 4; ++kt) {
            f16x8 wt, ut;
            #pragma unroll
            for (int j = 0; j < 8; ++j) {
                const int krow = kt * 32 + lc * 8 + j;
                wt[j] = (f16)W[(size_t)krow * 512 + g * 128 + u];
                ut[j] = (f16)U[(size_t)krow * 512 + g * 128 + u];
            }
            Wf[g][kt] = wt;  Uf[g][kt] = ut;
        }
    }
    float bias[4];
    #pragma unroll
    for (int g = 0; g < 4; ++g) bias[g] = Bv[g * 128 + u];

    // ---- precomputed swizzled addresses (lane constants)
    const int swz = (lr & 7) << 4;
    int raddr[2][4];
    #pragma unroll
    for (int a0 = 0; a0 < 2; ++a0)
        #pragma unroll
        for (int kt = 0; kt < 4; ++kt)
            raddr[a0][kt] = (((a0 * 8 + lr) * 256) + kt * 64 + lc * 16) ^ swz;
    int waddr[4];
    #pragma unroll
    for (int e = 0; e < 4; ++e)
        waddr[e] = ((8 + 4 * lc + e) * 256 + u * 2) ^ ((((4 * lc + e) & 7)) << 4);

    // ---- init LDS: zero both buffers, load x[0] into buf0 rows 0-7
    for (int i = tid; i < 3072; i += 512) ((float*)Ab)[i] = 0.0f;
    {
        const int flat = tid * 2, xr = flat >> 7, xc = flat & 127;
        const float2 xv = *(const float2*)(X + (size_t)(b0 + xr) * (T_STEPS * UNITS) + xc);
        const int byte = ((xr * 256 + xc * 2) ^ ((xr & 7) << 4));
        *(unsigned*)(Ab + byte) = pkh(xv.x, xv.y);
    }
    __syncthreads();

    float cst[4] = {0.f, 0.f, 0.f, 0.f};   // c1 (lanes<32) / c2 (lanes>=32)

    for (int k = 0; k <= T_STEPS; ++k) {
        const int rdo = (k & 1) * BUFB, wro = BUFB - rdo;

        // issue x[k+1] prefetch early (hides HBM latency under MFMA phase)
        float xa = 0.f, xb = 0.f; int xr = 0, xc = 0;
        if (k + 1 < T_STEPS) {
            const int flat = tid * 2; xr = flat >> 7; xc = flat & 127;
            const float2 xv = *(const float2*)(X + (size_t)(b0 + xr) * (T_STEPS * UNITS)
                                                 + (size_t)(k + 1) * UNITS + xc);
            xa = xv.x; xb = xv.y;
        }

        // ---- A fragments from LDS
        f16x8 A1[4], A2[4];
        #pragma unroll
        for (int kt = 0; kt < 4; ++kt) {
            A1[kt] = *(const f16x8*)(Ab + rdo + raddr[0][kt]);
            A2[kt] = *(const f16x8*)(Ab + rdo + raddr[1][kt]);
        }

        // ---- phase 1: g,o chains (16 MFMA, ILP 2)
        f32x4 accg = {bias[2], bias[2], bias[2], bias[2]};
        f32x4 acco = {bias[3], bias[3], bias[3], bias[3]};
        #pragma unroll
        for (int kt = 0; kt < 4; ++kt) {
            accg = MFMA16(A1[kt], Wf[2][kt], accg);
            acco = MFMA16(A1[kt], Wf[3][kt], acco);
        }
        #pragma unroll
        for (int kt = 0; kt < 4; ++kt) {
            accg = MFMA16(A2[kt], Uf[2][kt], accg);
            acco = MFMA16(A2[kt], Uf[3][kt], acco);
        }

        // ---- phase 2: i,f chains with g/o transcendentals spliced between
        // (trans pipe retires tanh/sigmoid while matrix pipe runs i/f MFMAs)
        f32x4 acci = {bias[0], bias[0], bias[0], bias[0]};
        f32x4 accf = {bias[1], bias[1], bias[1], bias[1]};
        float gg[4], oo[4];

        acci = MFMA16(A1[0], Wf[0][0], acci);  accf = MFMA16(A1[0], Wf[1][0], accf);
        gg[0] = tanhf_(accg[0]);
        acci = MFMA16(A1[1], Wf[0][1], acci);  accf = MFMA16(A1[1], Wf[1][1], accf);
        oo[0] = sigmoidf_(acco[0]);
        acci = MFMA16(A1[2], Wf[0][2], acci);  accf = MFMA16(A1[2], Wf[1][2], accf);
        gg[1] = tanhf_(accg[1]);
        acci = MFMA16(A1[3], Wf[0][3], acci);  accf = MFMA16(A1[3], Wf[1][3], accf);
        oo[1] = sigmoidf_(acco[1]);
        acci = MFMA16(A2[0], Uf[0][0], acci);  accf = MFMA16(A2[0], Uf[1][0], accf);
        gg[2] = tanhf_(accg[2]);
        acci = MFMA16(A2[1], Uf[0][1], acci);  accf = MFMA16(A2[1], Uf[1][1], accf);
        oo[2] = sigmoidf_(acco[2]);
        acci = MFMA16(A2[2], Uf[0][2], acci);  accf = MFMA16(A2[2], Uf[1][2], accf);
        gg[3] = tanhf_(accg[3]);
        acci = MFMA16(A2[3], Uf[0][3], acci);  accf = MFMA16(A2[3], Uf[1][3], accf);
        oo[3] = sigmoidf_(acco[3]);

        // ---- x[k+1] -> write buffer rows 0-7 (hides under i/f MFMA drain)
        if (k + 1 < T_STEPS) {
            const int byte = ((xr * 256 + xc * 2) ^ ((xr & 7) << 4));
            *(unsigned*)(Ab + wro + byte) = pkh(xa, xb);
        }

        // ---- tail: sigma(i,f) + c/h update
        const bool active = cell2 ? (k > 0) : (k < T_STEPS);
        float hq[4];
        #pragma unroll
        for (int e = 0; e < 4; ++e) {
            const float ig = sigmoidf_(acci[e]);
            const float fg = sigmoidf_(accf[e]);
            const float cn = fg * cst[e] + ig * gg[e];
            if (active) cst[e] = cn;
            hq[e] = oo[e] * tanhf_(cn);
        }

        // ---- write h1/h2 to wr buffer (row = 8 + 4*lc + e for both halves)
        if (active && k < T_STEPS) {
            #pragma unroll
            for (int e = 0; e < 4; ++e)
                *(f16*)(Ab + wro + waddr[e]) = (f16)hq[e];
        }

        // ---- final outputs
        if (k == T_STEPS - 1 && !cell2) {
            #pragma unroll
            for (int e = 0; e < 4; ++e)
                out[OUT_C1 + (size_t)(b0 + 4 * lc + e) * UNITS + u] = cst[e];
        }
        if (k == T_STEPS && cell2) {
            #pragma unroll
            for (int e = 0; e < 4; ++e)
                out[(size_t)(b0 + 4 * lc + e - 8) * UNITS + u] = hq[e];
        }
        __syncthreads();
    }
}

extern "C" void kernel_launch(void* const* d_in, const int* in_sizes, int n_in,
                              void* d_out, int out_size, void* d_ws, size_t ws_size,
                              hipStream_t stream) {
    const float* X  = (const float*)d_in[0];
    const float* W  = (const float*)d_in[1];
    const float* U  = (const float*)d_in[2];
    const float* Bv = (const float*)d_in[3];
    float* out = (float*)d_out;
    hipLaunchKernelGGL(lstm2_kernel, dim3(NBLK), dim3(512), 0, stream,
                       X, W, U, Bv, out);
}